// Round 4
// baseline (608.626 us; speedup 1.0000x reference)
//
#include <hip/hip_runtime.h>
#include <math.h>

#define N_NODES 50000
#define N_EDGES 1600000
#define HEADS 4
#define EMB 16
#define HOUT 64      // HEADS*EMB
#define HIDDEN 256
#define BATCH 1024
#define NEG_SLOPE 0.2f
#define ATS 50176    // padded node rows for agg_hi/lo (MFMA boundary-tile reads stay in-bounds)
#define SCAN_NB 196  // ceil(50000/256)
#define NXCD 8
#define DRANGE 6250  // N_NODES / NXCD
#define NSTRIP 196   // wave-strips in n-dim for the MFMA GEMM (49 blocks x 4 waves)
#define NT32 1563    // ceil(50000/32) valid 32-col tiles

typedef __attribute__((ext_vector_type(8))) short bf16x8;
typedef __attribute__((ext_vector_type(16))) float f32x16;

__device__ __forceinline__ float lrelu(float x) { return x > 0.f ? x : NEG_SLOPE * x; }

// round-to-nearest fp32 -> bf16, and back
__device__ __forceinline__ ushort f2bf(float f) {
    unsigned u = __float_as_uint(f);
    return (ushort)((u + 0x7fffu + ((u >> 16) & 1u)) >> 16);
}
__device__ __forceinline__ float bf2f(ushort h) { return __uint_as_float(((unsigned)h) << 16); }

// ---------------- K0: msg_emb = message @ fc_w + fc_b -> split-bf16 (hi/lo) [1024][64]
// gat_b term dropped: gat_b . msg_emb[b] is constant per output row b -> cancels in log_softmax.
__global__ void k_msgemb(const float* __restrict__ msg, const float* __restrict__ fcw,
                         const float* __restrict__ fcb,
                         ushort* __restrict__ msg_hi, ushort* __restrict__ msg_lo) {
    __shared__ float mrow[HIDDEN];
    int b = blockIdx.x;
    int j = threadIdx.x;  // 0..63
    for (int k = j; k < HIDDEN; k += 64) mrow[k] = msg[b * HIDDEN + k];
    __syncthreads();
    float acc = fcb[j];
    #pragma unroll 8
    for (int k = 0; k < HIDDEN; k++) acc += mrow[k] * fcw[k * HOUT + j];
    ushort hi = f2bf(acc);
    msg_hi[b * HOUT + j] = hi;
    msg_lo[b * HOUT + j] = f2bf(acc - bf2f(hi));
}

// ---------------- K1: h = x @ gat_w ; a_s, a_d per (node, head)
__global__ void k_node(const float* __restrict__ x, const float* __restrict__ gatw,
                       const float* __restrict__ atts, const float* __restrict__ attd,
                       float* __restrict__ h, float* __restrict__ a_s, float* __restrict__ a_d) {
    int tid = blockIdx.x * blockDim.x + threadIdx.x;
    int n = tid >> 6;
    int j = tid & 63;
    if (n >= N_NODES) return;
    float4 xv = ((const float4*)x)[n];
    float hv = xv.x * gatw[j] + xv.y * gatw[64 + j] + xv.z * gatw[128 + j] + xv.w * gatw[192 + j];
    h[n * 64 + j] = hv;
    float s = hv * atts[j];
    float d = hv * attd[j];
    for (int o = 8; o > 0; o >>= 1) {
        s += __shfl_down(s, o, 16);
        d += __shfl_down(d, o, 16);
    }
    if ((j & 15) == 0) {
        int head = j >> 4;
        a_s[n * 4 + head] = s;
        a_d[n * 4 + head] = d;
    }
}

// ---------------- K2a: count in-degree, dst-range partitioned per XCD
__global__ void k_count(const int* __restrict__ ei, int* __restrict__ cnt) {
    int p = blockIdx.x & 7;
    int tile = blockIdx.x >> 3;
    int e = tile * 256 + threadIdx.x;
    if (e < N_EDGES) {
        int d = ei[N_EDGES + e];
        if ((unsigned)(d - p * DRANGE) < (unsigned)DRANGE)
            atomicAdd(&cnt[d], 1);
    }
}

// ---------------- K2b: hierarchical exclusive scan over cnt[50000]
__global__ void k_scan1(const int* __restrict__ cnt, int* __restrict__ localx,
                        int* __restrict__ partial) {
    int b = blockIdx.x, t = threadIdx.x;
    int i = b * 256 + t;
    int v = (i < N_NODES) ? cnt[i] : 0;
    int lane = t & 63, w = t >> 6;
    int sv = v;
    #pragma unroll
    for (int o = 1; o < 64; o <<= 1) {
        int u = __shfl_up(sv, o);
        if (lane >= o) sv += u;
    }
    __shared__ int wsums[4];
    if (lane == 63) wsums[w] = sv;
    __syncthreads();
    int woff = 0;
    #pragma unroll
    for (int k = 0; k < 4; k++) woff += (k < w) ? wsums[k] : 0;
    if (i < N_NODES) localx[i] = woff + sv - v;
    if (t == 0) partial[b] = wsums[0] + wsums[1] + wsums[2] + wsums[3];
}

__global__ void k_scan2(const int* __restrict__ partial, int* __restrict__ blockoff,
                        int* __restrict__ rowptr_last) {
    int t = threadIdx.x;  // 256 threads
    int v = (t < SCAN_NB) ? partial[t] : 0;
    int lane = t & 63, w = t >> 6;
    int sv = v;
    #pragma unroll
    for (int o = 1; o < 64; o <<= 1) {
        int u = __shfl_up(sv, o);
        if (lane >= o) sv += u;
    }
    __shared__ int wsums[4];
    if (lane == 63) wsums[w] = sv;
    __syncthreads();
    int woff = 0;
    #pragma unroll
    for (int k = 0; k < 4; k++) woff += (k < w) ? wsums[k] : 0;
    int excl = woff + sv - v;
    if (t < SCAN_NB) blockoff[t] = excl;
    if (t == 255) rowptr_last[0] = excl + v;  // grand total -> rowptr[N_NODES]
}

__global__ void k_scan3(const int* __restrict__ localx, const int* __restrict__ blockoff,
                        int* __restrict__ rowptr, int* __restrict__ cursor) {
    int i = blockIdx.x * 256 + threadIdx.x;
    if (i < N_NODES) {
        int r = localx[i] + blockoff[blockIdx.x];
        rowptr[i] = r;
        cursor[i] = r;
    }
}

// ---------------- K2c: scatter src indices into CSR slots, dst-range partitioned per XCD
__global__ void k_scatter(const int* __restrict__ ei, int* __restrict__ cursor, int* __restrict__ csr) {
    int p = blockIdx.x & 7;
    int tile = blockIdx.x >> 3;
    int e = tile * 256 + threadIdx.x;
    if (e < N_EDGES) {
        int d = ei[N_EDGES + e];
        if ((unsigned)(d - p * DRANGE) < (unsigned)DRANGE) {
            int pos = atomicAdd(&cursor[d], 1);
            csr[pos] = ei[e];
        }
    }
}

// ---------------- K3: per-node softmax + aggregation (one wave per node).
// Epilogue emits split-bf16 agg rows [n][64] (hi/lo) -- the exact K-contiguous layout the
// MFMA B-fragments load -- so the fp32 agg array and the transpose kernel are gone.
__global__ __launch_bounds__(256, 8) void k_agg(const int* __restrict__ rowptr,
                      const int* __restrict__ csr,
                      const float* __restrict__ a_s, const float* __restrict__ a_d,
                      const float* __restrict__ h,
                      ushort* __restrict__ agg_hi, ushort* __restrict__ agg_lo) {
    __shared__ float salpha[4][64];
    int wid = threadIdx.x >> 6;
    int lane = threadIdx.x & 63;
    int n = blockIdx.x * 4 + wid;
    if (n >= N_NODES) return;
    int beg = rowptr[n], end = rowptr[n + 1];
    int head = lane & 3, eoff = lane >> 2;
    float adh = a_d[n * 4 + head];

    // phase 1: denom = sum exp(e) per head; lanes split 16 edges x 4 heads
    float s = 0.f;
    for (int i = beg + eoff; i < end; i += 16) {
        int src = csr[i];
        s += __expf(lrelu(a_s[src * 4 + head] + adh));
    }
    #pragma unroll
    for (int o = 4; o < 64; o <<= 1) s += __shfl_xor(s, o);
    float inv = 1.f / (s + 1e-16f);

    // phase 2: chunks of 16 edges; each lane computes one alpha, stage in LDS,
    // then lanes = features accumulate with readlane'd src + broadcast alpha.
    float acc = 0.f;
    const float* ap = &salpha[wid][(lane >> 4) * 16];
    for (int base = beg; base < end; base += 16) {
        int e = base + eoff;
        int ec = (e < end) ? e : (end - 1);
        int src = csr[ec];
        float ev = lrelu(a_s[src * 4 + head] + adh);
        float alpha = (e < end) ? __expf(ev) * inv : 0.f;
        salpha[wid][head * 16 + eoff] = alpha;
        __builtin_amdgcn_wave_barrier();
        #pragma unroll
        for (int c = 0; c < 4; c++) {
            float4 av = *(const float4*)(ap + c * 4);
            int s0 = __builtin_amdgcn_readlane(src, c * 16 + 0);
            int s1 = __builtin_amdgcn_readlane(src, c * 16 + 4);
            int s2 = __builtin_amdgcn_readlane(src, c * 16 + 8);
            int s3 = __builtin_amdgcn_readlane(src, c * 16 + 12);
            acc = fmaf(av.x, h[(size_t)s0 * 64 + lane], acc);
            acc = fmaf(av.y, h[(size_t)s1 * 64 + lane], acc);
            acc = fmaf(av.z, h[(size_t)s2 * 64 + lane], acc);
            acc = fmaf(av.w, h[(size_t)s3 * 64 + lane], acc);
        }
        __builtin_amdgcn_wave_barrier();
    }
    ushort hi = f2bf(acc);
    agg_hi[(size_t)n * 64 + lane] = hi;
    agg_lo[(size_t)n * 64 + lane] = f2bf(acc - bf2f(hi));
}

// ---------------- MFMA GEMM core: logits[b][n] = sum_k msg[b][k]*agg[n][k], split-bf16
// 3-term (hi*hi + hi*lo + lo*hi), fp32 accumulate. mfma_f32_32x32x16_bf16:
//   A lane layout: A[lane&31][(lane>>5)*8 + j]  (8 K-contiguous bf16 = one 16B load)
//   B lane layout: B[(lane>>5)*8 + j][lane&31]  -> agg row-major [n][k] fits directly
//   D layout (m74/m101-verified): col=lane&31, row=(reg&3)+8*(reg>>2)+4*(lane>>5)
// Wave = one 32-row b-group x 8 consecutive 32-col n-tiles.

// ---------------- K4a: pass A -- S-partials: ps[b][strip] = sum_n exp(dot)
// (no max-shift: |dot| <~ 45 << 88, fp32-safe -- validated in rounds 1-3)
__global__ __launch_bounds__(256, 4) void k_logsum(const ushort* __restrict__ agg_hi,
    const ushort* __restrict__ agg_lo, const ushort* __restrict__ msg_hi,
    const ushort* __restrict__ msg_lo, float* __restrict__ ps) {
    int t = threadIdx.x;
    int lane = t & 63, wid = t >> 6;
    int l31 = lane & 31, half = lane >> 5;
    int b0 = blockIdx.y * 32;
    int gw = blockIdx.x * 4 + wid;  // 0..195 strip id

    const ushort* mh = msg_hi + (size_t)(b0 + l31) * HOUT + half * 8;
    const ushort* ml = msg_lo + (size_t)(b0 + l31) * HOUT + half * 8;
    bf16x8 mH[4], mL[4];
    #pragma unroll
    for (int ks = 0; ks < 4; ks++) {
        mH[ks] = *(const bf16x8*)(mh + ks * 16);
        mL[ks] = *(const bf16x8*)(ml + ks * 16);
    }

    float sacc[16];
    #pragma unroll
    for (int r = 0; r < 16; r++) sacc[r] = 0.f;

    for (int i = 0; i < 8; i++) {
        int tile = gw * 8 + i;
        int n0 = tile * 32;
        if (n0 >= N_NODES) break;
        const ushort* ah = agg_hi + (size_t)(n0 + l31) * HOUT + half * 8;
        const ushort* al = agg_lo + (size_t)(n0 + l31) * HOUT + half * 8;
        f32x16 acc;
        #pragma unroll
        for (int r = 0; r < 16; r++) acc[r] = 0.f;
        #pragma unroll
        for (int ks = 0; ks < 4; ks++) {
            bf16x8 aH = *(const bf16x8*)(ah + ks * 16);
            bf16x8 aL = *(const bf16x8*)(al + ks * 16);
            acc = __builtin_amdgcn_mfma_f32_32x32x16_bf16(mH[ks], aH, acc, 0, 0, 0);
            acc = __builtin_amdgcn_mfma_f32_32x32x16_bf16(mH[ks], aL, acc, 0, 0, 0);
            acc = __builtin_amdgcn_mfma_f32_32x32x16_bf16(mL[ks], aH, acc, 0, 0, 0);
        }
        bool valid = (n0 + l31) < N_NODES;  // pad cols masked (pad memory is garbage)
        #pragma unroll
        for (int r = 0; r < 16; r++) sacc[r] += valid ? __expf(acc[r]) : 0.f;
    }
    // reduce over the 32 cols within each lane-half
    #pragma unroll
    for (int r = 0; r < 16; r++) {
        float s = sacc[r];
        #pragma unroll
        for (int o = 1; o < 32; o <<= 1) s += __shfl_xor(s, o);
        sacc[r] = s;
    }
    if (l31 == 0) {
        #pragma unroll
        for (int r = 0; r < 16; r++) {
            int b = b0 + (r & 3) + 8 * (r >> 2) + 4 * half;
            ps[(size_t)b * NSTRIP + gw] = sacc[r];
        }
    }
}

// ---------------- K5: rowls[b] = log( sum_strips ps )
__global__ void k_rowstats(const float* __restrict__ ps, float* __restrict__ rowls) {
    int b = blockIdx.x * blockDim.x + threadIdx.x;
    if (b >= BATCH) return;
    float S = 0.f;
    for (int i = 0; i < NSTRIP; i++) S += ps[b * NSTRIP + i];
    rowls[b] = logf(S);
}

// ---------------- K4b: pass B -- recompute dot (MFMA, ~free) and write final
// log-softmax once: out = dot - rowls[b]. Single 205 MB output write, no fixup pass.
__global__ __launch_bounds__(256, 4) void k_logits_w(const ushort* __restrict__ agg_hi,
    const ushort* __restrict__ agg_lo, const ushort* __restrict__ msg_hi,
    const ushort* __restrict__ msg_lo, const float* __restrict__ rowls,
    float* __restrict__ out) {
    int t = threadIdx.x;
    int lane = t & 63, wid = t >> 6;
    int l31 = lane & 31, half = lane >> 5;
    int b0 = blockIdx.y * 32;
    int gw = blockIdx.x * 4 + wid;

    const ushort* mh = msg_hi + (size_t)(b0 + l31) * HOUT + half * 8;
    const ushort* ml = msg_lo + (size_t)(b0 + l31) * HOUT + half * 8;
    bf16x8 mH[4], mL[4];
    #pragma unroll
    for (int ks = 0; ks < 4; ks++) {
        mH[ks] = *(const bf16x8*)(mh + ks * 16);
        mL[ks] = *(const bf16x8*)(ml + ks * 16);
    }
    float sub[16];
    int brow[16];
    #pragma unroll
    for (int r = 0; r < 16; r++) {
        brow[r] = b0 + (r & 3) + 8 * (r >> 2) + 4 * half;
        sub[r] = rowls[brow[r]];
    }

    for (int i = 0; i < 8; i++) {
        int tile = gw * 8 + i;
        int n0 = tile * 32;
        if (n0 >= N_NODES) break;
        const ushort* ah = agg_hi + (size_t)(n0 + l31) * HOUT + half * 8;
        const ushort* al = agg_lo + (size_t)(n0 + l31) * HOUT + half * 8;
        f32x16 acc;
        #pragma unroll
        for (int r = 0; r < 16; r++) acc[r] = 0.f;
        #pragma unroll
        for (int ks = 0; ks < 4; ks++) {
            bf16x8 aH = *(const bf16x8*)(ah + ks * 16);
            bf16x8 aL = *(const bf16x8*)(al + ks * 16);
            acc = __builtin_amdgcn_mfma_f32_32x32x16_bf16(mH[ks], aH, acc, 0, 0, 0);
            acc = __builtin_amdgcn_mfma_f32_32x32x16_bf16(mH[ks], aL, acc, 0, 0, 0);
            acc = __builtin_amdgcn_mfma_f32_32x32x16_bf16(mL[ks], aH, acc, 0, 0, 0);
        }
        int n = n0 + l31;
        if (n < N_NODES) {
            #pragma unroll
            for (int r = 0; r < 16; r++)
                out[(size_t)brow[r] * N_NODES + n] = acc[r] - sub[r];
        }
    }
}

extern "C" void kernel_launch(void* const* d_in, const int* in_sizes, int n_in,
                              void* d_out, int out_size, void* d_ws, size_t ws_size,
                              hipStream_t stream) {
    const float* message = (const float*)d_in[0];
    const float* x       = (const float*)d_in[1];
    const int*   ei      = (const int*)d_in[2];
    const float* gat_w   = (const float*)d_in[3];
    const float* att_src = (const float*)d_in[4];
    const float* att_dst = (const float*)d_in[5];
    const float* fc_w    = (const float*)d_in[7];
    const float* fc_b    = (const float*)d_in[8];
    float* out = (float*)d_out;

    float* ws      = (float*)d_ws;
    float* a_s     = ws;                                   // 50000*4
    float* a_d     = a_s + (size_t)N_NODES * HEADS;        // 50000*4
    float* hbuf    = a_d + (size_t)N_NODES * HEADS;        // 50000*64
    float* ps      = hbuf + (size_t)N_NODES * HOUT;        // 1024*196
    float* rowls   = ps + (size_t)BATCH * NSTRIP;          // 1024
    ushort* msg_hi = (ushort*)(rowls + BATCH);             // 1024*64
    ushort* msg_lo = msg_hi + (size_t)BATCH * HOUT;        // 1024*64
    ushort* agg_hi = msg_lo + (size_t)BATCH * HOUT;        // ATS*64 (rows >= 50000 unwritten)
    ushort* agg_lo = agg_hi + (size_t)ATS * HOUT;          // ATS*64
    int*   cnt     = (int*)(agg_lo + (size_t)ATS * HOUT);  // 50000
    int*   rowptr  = cnt + N_NODES;                        // 50001
    int*   cursor  = rowptr + N_NODES + 1;                 // 50000
    int*   csr     = cursor + N_NODES;                     // 1600000
    int*   localx  = csr + N_EDGES;                        // 50000
    int*   partial = localx + N_NODES;                     // 196
    int*   blockoff= partial + SCAN_NB;                    // 196

    hipMemsetAsync(cnt, 0, N_NODES * sizeof(int), stream);
    k_msgemb<<<BATCH, 64, 0, stream>>>(message, fc_w, fc_b, msg_hi, msg_lo);
    k_node<<<(N_NODES * 64 + 255) / 256, 256, 0, stream>>>(x, gat_w, att_src, att_dst, hbuf, a_s, a_d);
    k_count<<<NXCD * (N_EDGES / 256), 256, 0, stream>>>(ei, cnt);
    k_scan1<<<SCAN_NB, 256, 0, stream>>>(cnt, localx, partial);
    k_scan2<<<1, 256, 0, stream>>>(partial, blockoff, rowptr + N_NODES);
    k_scan3<<<SCAN_NB, 256, 0, stream>>>(localx, blockoff, rowptr, cursor);
    k_scatter<<<NXCD * (N_EDGES / 256), 256, 0, stream>>>(ei, cursor, csr);
    k_agg<<<(N_NODES + 3) / 4, 256, 0, stream>>>(rowptr, csr, a_s, a_d, hbuf, agg_hi, agg_lo);
    dim3 g4(49, 32);
    k_logsum<<<g4, 256, 0, stream>>>(agg_hi, agg_lo, msg_hi, msg_lo, ps);
    k_rowstats<<<4, 256, 0, stream>>>(ps, rowls);
    k_logits_w<<<g4, 256, 0, stream>>>(agg_hi, agg_lo, msg_hi, msg_lo, rowls, out);
}